// Round 3
// baseline (661.535 us; speedup 1.0000x reference)
//
#include <hip/hip_runtime.h>
#include <math.h>

// DeltaNetTemporal: B=16, N=4096, C=256, H=4, D=64.
// Interface dtypes: ALL fp32 (inputs and both outputs), per reference.
// Internal compute: fp16 MFMA GEMMs (fp32 accumulate), fp32 state math.
// Chunked over 4 batch-groups to keep workspace at 26.25 MB:
//   beta (full) -> 4x [ proj GEMM -> state_pass (ynorm in-place, fp16) -> out GEMM ] -> finalize_S
// Workspace: qkv_chunk f16 25165824 + beta 1048576 + sums 32768 = 26.25 MB.

typedef _Float16 f16;
typedef f16 f16x8 __attribute__((ext_vector_type(8)));
typedef float f32x4 __attribute__((ext_vector_type(4)));

// 8 fp32 -> 8 fp16
__device__ __forceinline__ f16x8 cvt8(const float* q) {
  float4 a = *(const float4*)q;
  float4 b = *(const float4*)(q + 4);
  f16x8 r;
  r[0] = (f16)a.x; r[1] = (f16)a.y; r[2] = (f16)a.z; r[3] = (f16)a.w;
  r[4] = (f16)b.x; r[5] = (f16)b.y; r[6] = (f16)b.z; r[7] = (f16)b.w;
  return r;
}

// ---------------- beta ----------------
__global__ __launch_bounds__(256) void beta_kernel(
    const float* __restrict__ x, const float* __restrict__ Wb,
    float* __restrict__ betaArr) {
  int t = threadIdx.x;
  int wave = t >> 6, lane = t & 63;
  size_t row = (size_t)blockIdx.x * 4 + wave;  // 0..65535 = b*4096+n
  float4 xv = *(const float4*)(x + row * 256 + lane * 4);
  float p[4];
#pragma unroll
  for (int h = 0; h < 4; ++h) {
    float4 wv = *(const float4*)(Wb + h * 256 + lane * 4);
    float s = xv.x * wv.x + xv.y * wv.y + xv.z * wv.z + xv.w * wv.w;
#pragma unroll
    for (int off = 32; off; off >>= 1) s += __shfl_xor(s, off);
    p[h] = s;
  }
  if (lane < 4) {
    float z = p[lane];
    size_t b = row >> 12, n = row & 4095;
    betaArr[((b * 4 + (size_t)lane) << 12) + n] = 1.f / (1.f + __expf(-z));
  }
}

// ---------------- fp16 MFMA GEMM: C[128-row tiles] = A @ W^T ----------------
// AT = float (x, converted on stage) or f16 (workspace ynorm). CT = f16 or float.
template <typename AT, typename CT>
__global__ __launch_bounds__(256) void gemm_bt(
    const AT* __restrict__ A, int lda, int m_base,
    const float* __restrict__ B0, const float* __restrict__ B1,
    const float* __restrict__ B2, CT* __restrict__ C, int ldc) {
  __shared__ f16 As[128][72];  // +8 pad
  __shared__ f16 Bs[128][72];
  const int t = threadIdx.x;
  const int m0 = blockIdx.y * 128;
  const int n0 = blockIdx.x * 128;
  const float* Bsel = (n0 < 256) ? B0 : ((n0 < 512) ? B1 : B2);
  const int nin = n0 & 255;
  const int wave = t >> 6, lane = t & 63;
  const int wm = (wave >> 1) * 64, wn = (wave & 1) * 64;
  const int fr = lane & 15, fq = lane >> 4;
  f32x4 acc[4][4] = {};
#pragma unroll 1
  for (int kt = 0; kt < 4; ++kt) {
    const int k0 = kt * 64;
#pragma unroll
    for (int i = 0; i < 4; ++i) {
      int id = i * 256 + t;
      int row = id >> 3, cc = id & 7;
      if constexpr (__is_same(AT, float)) {
        *(f16x8*)&As[row][cc * 8] =
            cvt8(A + (size_t)(m_base + m0 + row) * lda + k0 + cc * 8);
      } else {
        *(uint4*)&As[row][cc * 8] =
            *(const uint4*)(A + (size_t)(m_base + m0 + row) * lda + k0 + cc * 8);
      }
      *(f16x8*)&Bs[row][cc * 8] =
          cvt8(Bsel + (size_t)(nin + row) * 256 + k0 + cc * 8);
    }
    __syncthreads();
#pragma unroll
    for (int ks = 0; ks < 2; ++ks) {
      f16x8 afr[4], bfr[4];
#pragma unroll
      for (int mi = 0; mi < 4; ++mi)
        afr[mi] = *(const f16x8*)&As[wm + mi * 16 + fr][ks * 32 + fq * 8];
#pragma unroll
      for (int ni = 0; ni < 4; ++ni)
        bfr[ni] = *(const f16x8*)&Bs[wn + ni * 16 + fr][ks * 32 + fq * 8];
#pragma unroll
      for (int mi = 0; mi < 4; ++mi)
#pragma unroll
        for (int ni = 0; ni < 4; ++ni)
          acc[mi][ni] = __builtin_amdgcn_mfma_f32_16x16x32_f16(
              afr[mi], bfr[ni], acc[mi][ni], 0, 0, 0);
    }
    __syncthreads();
  }
#pragma unroll
  for (int mi = 0; mi < 4; ++mi)
#pragma unroll
    for (int ni = 0; ni < 4; ++ni)
#pragma unroll
      for (int rr = 0; rr < 4; ++rr) {
        int row = m0 + wm + mi * 16 + fq * 4 + rr;  // C/D: row=(lane>>4)*4+reg
        int col = n0 + wn + ni * 16 + fr;           //      col=lane&15
        C[(size_t)row * ldc + col] = (CT)acc[mi][ni][rr];
      }
}

// ---------------- state pass (per chunk of 4 batches) ----------------
// block = 256 thr = (h = t>>6) x (i = t&63); writes RMSNorm'd y in-place into q slot.
__global__ __launch_bounds__(256) void state_pass(
    f16* __restrict__ qkv, const float* __restrict__ S, int b_base,
    const float* __restrict__ betaArr, const float* __restrict__ g_rms,
    float* __restrict__ err_sum, float* __restrict__ key_sum) {
  const int t = threadIdx.x;
  const int h = t >> 6, lane = t & 63;
  const int b = b_base + blockIdx.y;  // global batch
  const int ntile = blockIdx.x;
  float sd[64];  // 0.95 * S[b][h][lane][:] in registers
  {
    const float* Srow = S + (((size_t)b * 4 + h) * 64 + lane) * 64;
#pragma unroll
    for (int j4 = 0; j4 < 16; ++j4) {
      float4 v = *(const float4*)(Srow + j4 * 4);
      sd[j4 * 4 + 0] = 0.95f * v.x;
      sd[j4 * 4 + 1] = 0.95f * v.y;
      sd[j4 * 4 + 2] = 0.95f * v.z;
      sd[j4 * 4 + 3] = 0.95f * v.w;
    }
  }
  float g = g_rms[t];
  __shared__ float qs[256], ks[256], red[8];
  const float* qh = &qs[h * 64];
  const float* kh = &ks[h * 64];
  const float* betaBH = betaArr + (((size_t)b * 4 + h) << 12) + (size_t)ntile * 64;
  float errA = 0.f, keyA = 0.f;
  for (int r = 0; r < 64; ++r) {
    size_t mloc = (size_t)blockIdx.y * 4096 + (size_t)ntile * 64 + r;  // row in chunk
    f16* qp = qkv + mloc * 768;
    float qv = (float)qp[t];
    float kraw = (float)qp[256 + t];
    float vv = (float)qp[512 + t];
    float ke = kraw > 0.f ? kraw + 1.f : __expf(kraw);  // elu(k)+1
    float s2 = ke * ke;
#pragma unroll
    for (int off = 32; off; off >>= 1) s2 += __shfl_xor(s2, off);
    float ktv = ke / (sqrtf(s2) + 1e-6f);
    keyA += ktv;
    qs[t] = qv;
    ks[t] = ktv;
    __syncthreads();
    float y = 0.f, pr = 0.f;
#pragma unroll
    for (int j4 = 0; j4 < 16; ++j4) {
      float4 qq = *(const float4*)(qh + j4 * 4);  // LDS broadcast reads
      float4 kk = *(const float4*)(kh + j4 * 4);
      y  += sd[j4*4+0]*qq.x + sd[j4*4+1]*qq.y + sd[j4*4+2]*qq.z + sd[j4*4+3]*qq.w;
      pr += sd[j4*4+0]*kk.x + sd[j4*4+1]*kk.y + sd[j4*4+2]*kk.z + sd[j4*4+3]*kk.w;
    }
    errA += betaBH[r] * (vv - pr);
    float w2 = y * y;
#pragma unroll
    for (int off = 32; off; off >>= 1) w2 += __shfl_xor(w2, off);
    if (lane == 0) red[h + 4 * (r & 1)] = w2;  // double-buffered slots
    __syncthreads();
    const float* rd = &red[4 * (r & 1)];
    float tot = rd[0] + rd[1] + rd[2] + rd[3];
    float scale = rsqrtf(tot * (1.f / 256.f) + 1e-6f);
    qp[t] = (f16)(y * scale * g);  // in-place: ynorm into q slot
  }
  atomicAdd(&err_sum[(size_t)b * 256 + t], errA);
  atomicAdd(&key_sum[(size_t)b * 256 + t], keyA);
}

// ---------------- S_new finalize ----------------
__global__ __launch_bounds__(256) void finalize_S(
    const float* __restrict__ S, const float* __restrict__ err_sum,
    const float* __restrict__ key_sum, float* __restrict__ Sout) {
  int bh = blockIdx.x;  // b*4+h
  int b = bh >> 2;
  const float* eb = err_sum + (size_t)b * 256 + (size_t)(bh & 3) * 64;
  const float* kb = key_sum + (size_t)b * 256 + (size_t)(bh & 3) * 64;
  for (int idx = threadIdx.x; idx < 4096; idx += 256) {
    int i = idx >> 6, j = idx & 63;
    float sdv = 0.95f * S[(size_t)bh * 4096 + idx];
    float v = sdv + (eb[i] * (1.f / 4096.f)) * (kb[j] * (1.f / 4096.f));
    v = fminf(10.f, fmaxf(-10.f, v));
    Sout[(size_t)bh * 4096 + idx] = v;
  }
}

extern "C" void kernel_launch(void* const* d_in, const int* in_sizes, int n_in,
                              void* d_out, int out_size, void* d_ws, size_t ws_size,
                              hipStream_t stream) {
  const float* x  = (const float*)d_in[0];
  const float* S  = (const float*)d_in[1];
  const float* Wq = (const float*)d_in[2];
  const float* Wk = (const float*)d_in[3];
  const float* Wv = (const float*)d_in[4];
  const float* Wb = (const float*)d_in[5];
  const float* Wo = (const float*)d_in[6];
  const float* g  = (const float*)d_in[7];

  char* w = (char*)d_ws;
  f16*   qkvc    = (f16*)w;                     // 16384*768*2 = 25,165,824
  float* betaArr = (float*)(w + 25165824);      // 16*4*4096*4 =  1,048,576
  float* sums    = (float*)(w + 26214400);      // 2*4096*4    =     32,768
  float* err_sum = sums;
  float* key_sum = sums + 4096;

  float* out  = (float*)d_out;                  // [16,4096,256] fp32
  float* Sout = out + (size_t)16 * 4096 * 256;  // [16,4,64,64]  fp32

  hipMemsetAsync(sums, 0, 32768, stream);
  beta_kernel<<<16384, 256, 0, stream>>>(x, Wb, betaArr);
  for (int c = 0; c < 4; ++c) {
    int m_base = c * 16384;  // row chunk = 4 batches
    gemm_bt<float, f16><<<dim3(6, 128), 256, 0, stream>>>(
        x, 256, m_base, Wq, Wk, Wv, qkvc, 768);
    state_pass<<<dim3(64, 4), 256, 0, stream>>>(qkvc, S, c * 4, betaArr, g,
                                                err_sum, key_sum);
    gemm_bt<f16, float><<<dim3(2, 128), 256, 0, stream>>>(
        qkvc, 768, 0, Wo, Wo, Wo, out + (size_t)m_base * 256, 256);
  }
  finalize_S<<<64, 256, 0, stream>>>(S, err_sum, key_sum, Sout);
}

// Round 4
// 516.005 us; speedup vs baseline: 1.2820x; 1.2820x over previous
//
#include <hip/hip_runtime.h>
#include <math.h>

// DeltaNetTemporal: B=16, N=4096, C=256, H=4, D=64.
// Interface dtypes: ALL fp32 (inputs and both outputs), per reference.
// Internal compute: fp16 MFMA GEMMs (fp32 accumulate), fp32 state math.
// Chunked over 4 batch-groups to keep workspace at 26.25 MB:
//   beta (full) -> 4x [ proj GEMM -> state_pass (ynorm in-place, fp16) -> out GEMM ] -> finalize_S
// R4: state_pass restructured: 16-row tiles (4 blocks/CU), wave-local q/k exchange
//     (no barrier), deferred RMSNorm (1 barrier/block instead of 128).

typedef _Float16 f16;
typedef f16 f16x8 __attribute__((ext_vector_type(8)));
typedef float f32x4 __attribute__((ext_vector_type(4)));

// 8 fp32 -> 8 fp16
__device__ __forceinline__ f16x8 cvt8(const float* q) {
  float4 a = *(const float4*)q;
  float4 b = *(const float4*)(q + 4);
  f16x8 r;
  r[0] = (f16)a.x; r[1] = (f16)a.y; r[2] = (f16)a.z; r[3] = (f16)a.w;
  r[4] = (f16)b.x; r[5] = (f16)b.y; r[6] = (f16)b.z; r[7] = (f16)b.w;
  return r;
}

// ---------------- beta ----------------
__global__ __launch_bounds__(256) void beta_kernel(
    const float* __restrict__ x, const float* __restrict__ Wb,
    float* __restrict__ betaArr) {
  int t = threadIdx.x;
  int wave = t >> 6, lane = t & 63;
  size_t row = (size_t)blockIdx.x * 4 + wave;  // 0..65535 = b*4096+n
  float4 xv = *(const float4*)(x + row * 256 + lane * 4);
  float p[4];
#pragma unroll
  for (int h = 0; h < 4; ++h) {
    float4 wv = *(const float4*)(Wb + h * 256 + lane * 4);
    float s = xv.x * wv.x + xv.y * wv.y + xv.z * wv.z + xv.w * wv.w;
#pragma unroll
    for (int off = 32; off; off >>= 1) s += __shfl_xor(s, off);
    p[h] = s;
  }
  if (lane < 4) {
    float z = p[lane];
    size_t b = row >> 12, n = row & 4095;
    betaArr[((b * 4 + (size_t)lane) << 12) + n] = 1.f / (1.f + __expf(-z));
  }
}

// ---------------- fp16 MFMA GEMM: C[128-row tiles] = A @ W^T ----------------
// AT = float (x, converted on stage) or f16 (workspace ynorm). CT = f16 or float.
template <typename AT, typename CT>
__global__ __launch_bounds__(256) void gemm_bt(
    const AT* __restrict__ A, int lda, int m_base,
    const float* __restrict__ B0, const float* __restrict__ B1,
    const float* __restrict__ B2, CT* __restrict__ C, int ldc) {
  __shared__ f16 As[128][72];  // +8 pad
  __shared__ f16 Bs[128][72];
  const int t = threadIdx.x;
  const int m0 = blockIdx.y * 128;
  const int n0 = blockIdx.x * 128;
  const float* Bsel = (n0 < 256) ? B0 : ((n0 < 512) ? B1 : B2);
  const int nin = n0 & 255;
  const int wave = t >> 6, lane = t & 63;
  const int wm = (wave >> 1) * 64, wn = (wave & 1) * 64;
  const int fr = lane & 15, fq = lane >> 4;
  f32x4 acc[4][4] = {};
#pragma unroll 1
  for (int kt = 0; kt < 4; ++kt) {
    const int k0 = kt * 64;
#pragma unroll
    for (int i = 0; i < 4; ++i) {
      int id = i * 256 + t;
      int row = id >> 3, cc = id & 7;
      if constexpr (__is_same(AT, float)) {
        *(f16x8*)&As[row][cc * 8] =
            cvt8(A + (size_t)(m_base + m0 + row) * lda + k0 + cc * 8);
      } else {
        *(uint4*)&As[row][cc * 8] =
            *(const uint4*)(A + (size_t)(m_base + m0 + row) * lda + k0 + cc * 8);
      }
      *(f16x8*)&Bs[row][cc * 8] =
          cvt8(Bsel + (size_t)(nin + row) * 256 + k0 + cc * 8);
    }
    __syncthreads();
#pragma unroll
    for (int ks = 0; ks < 2; ++ks) {
      f16x8 afr[4], bfr[4];
#pragma unroll
      for (int mi = 0; mi < 4; ++mi)
        afr[mi] = *(const f16x8*)&As[wm + mi * 16 + fr][ks * 32 + fq * 8];
#pragma unroll
      for (int ni = 0; ni < 4; ++ni)
        bfr[ni] = *(const f16x8*)&Bs[wn + ni * 16 + fr][ks * 32 + fq * 8];
#pragma unroll
      for (int mi = 0; mi < 4; ++mi)
#pragma unroll
        for (int ni = 0; ni < 4; ++ni)
          acc[mi][ni] = __builtin_amdgcn_mfma_f32_16x16x32_f16(
              afr[mi], bfr[ni], acc[mi][ni], 0, 0, 0);
    }
    __syncthreads();
  }
#pragma unroll
  for (int mi = 0; mi < 4; ++mi)
#pragma unroll
    for (int ni = 0; ni < 4; ++ni)
#pragma unroll
      for (int rr = 0; rr < 4; ++rr) {
        int row = m0 + wm + mi * 16 + fq * 4 + rr;  // C/D: row=(lane>>4)*4+reg
        int col = n0 + wn + ni * 16 + fr;           //      col=lane&15
        C[(size_t)row * ldc + col] = (CT)acc[mi][ni][rr];
      }
}

// ---------------- state pass (per chunk of 4 batches) ----------------
// block = 256 thr = (h = t>>6) x (i = t&63); one block per (b, 16-row tile).
// q/k exchange is wave-local (head h == wave h): no __syncthreads needed.
// RMSNorm deferred: y -> LDS ybuf, one barrier, then normalize+store.
__global__ __launch_bounds__(256) void state_pass(
    f16* __restrict__ qkv, const float* __restrict__ S, int b_base,
    const float* __restrict__ betaArr, const float* __restrict__ g_rms,
    float* __restrict__ err_sum, float* __restrict__ key_sum) {
  const int t = threadIdx.x;
  const int h = t >> 6, lane = t & 63;
  const int b = b_base + blockIdx.y;  // global batch
  const int tile = blockIdx.x;        // 16-row tile
  float sd[64];  // 0.95 * S[b][h][lane][:] in registers
  {
    const float* Srow = S + (((size_t)b * 4 + h) * 64 + lane) * 64;
#pragma unroll
    for (int j4 = 0; j4 < 16; ++j4) {
      float4 v = *(const float4*)(Srow + j4 * 4);
      sd[j4 * 4 + 0] = 0.95f * v.x;
      sd[j4 * 4 + 1] = 0.95f * v.y;
      sd[j4 * 4 + 2] = 0.95f * v.z;
      sd[j4 * 4 + 3] = 0.95f * v.w;
    }
  }
  float g = g_rms[t];
  __shared__ float qs[256], ks[256], red[64];  // red[h][r]: per-(head,row) sumsq
  __shared__ f16 ybuf[16][256];                // un-normalized y tile
  const float* qh = &qs[h * 64];
  const float* kh = &ks[h * 64];
  const float* betaBH = betaArr + (((size_t)b * 4 + h) << 12) + (size_t)tile * 16;
  const size_t row0 = (size_t)blockIdx.y * 4096 + (size_t)tile * 16;
  float errA = 0.f, keyA = 0.f;
#pragma unroll 1
  for (int r = 0; r < 16; ++r) {
    f16* qp = qkv + (row0 + r) * 768;
    float qv = (float)qp[t];
    float kraw = (float)qp[256 + t];
    float vv = (float)qp[512 + t];
    float ke = kraw > 0.f ? kraw + 1.f : __expf(kraw);  // elu(k)+1
    float s2 = ke * ke;
#pragma unroll
    for (int off = 32; off; off >>= 1) s2 += __shfl_xor(s2, off);
    float ktv = ke / (sqrtf(s2) + 1e-6f);
    keyA += ktv;
    qs[t] = qv;
    ks[t] = ktv;
    __builtin_amdgcn_wave_barrier();  // same-wave LDS ordering only
    float y = 0.f, pr = 0.f;
#pragma unroll
    for (int j4 = 0; j4 < 16; ++j4) {
      float4 qq = *(const float4*)(qh + j4 * 4);  // wave-local LDS reads
      float4 kk = *(const float4*)(kh + j4 * 4);
      y  += sd[j4*4+0]*qq.x + sd[j4*4+1]*qq.y + sd[j4*4+2]*qq.z + sd[j4*4+3]*qq.w;
      pr += sd[j4*4+0]*kk.x + sd[j4*4+1]*kk.y + sd[j4*4+2]*kk.z + sd[j4*4+3]*kk.w;
    }
    __builtin_amdgcn_wave_barrier();  // keep qs/ks live until reads done
    errA += betaBH[r] * (vv - pr);
    float w2 = y * y;
#pragma unroll
    for (int off = 32; off; off >>= 1) w2 += __shfl_xor(w2, off);
    if (lane == 0) red[h * 16 + r] = w2;
    ybuf[r][t] = (f16)y;
  }
  __syncthreads();  // the only block-wide barrier
#pragma unroll 1
  for (int r = 0; r < 16; ++r) {
    float tot = red[r] + red[16 + r] + red[32 + r] + red[48 + r];
    float scale = rsqrtf(tot * (1.f / 256.f) + 1e-6f);
    f16* qp = qkv + (row0 + r) * 768;
    qp[t] = (f16)((float)ybuf[r][t] * scale * g);  // in-place: ynorm into q slot
  }
  atomicAdd(&err_sum[(size_t)b * 256 + t], errA);
  atomicAdd(&key_sum[(size_t)b * 256 + t], keyA);
}

// ---------------- S_new finalize ----------------
__global__ __launch_bounds__(256) void finalize_S(
    const float* __restrict__ S, const float* __restrict__ err_sum,
    const float* __restrict__ key_sum, float* __restrict__ Sout) {
  int bh = blockIdx.x;  // b*4+h
  int b = bh >> 2;
  const float* eb = err_sum + (size_t)b * 256 + (size_t)(bh & 3) * 64;
  const float* kb = key_sum + (size_t)b * 256 + (size_t)(bh & 3) * 64;
  for (int idx = threadIdx.x; idx < 4096; idx += 256) {
    int i = idx >> 6, j = idx & 63;
    float sdv = 0.95f * S[(size_t)bh * 4096 + idx];
    float v = sdv + (eb[i] * (1.f / 4096.f)) * (kb[j] * (1.f / 4096.f));
    v = fminf(10.f, fmaxf(-10.f, v));
    Sout[(size_t)bh * 4096 + idx] = v;
  }
}

extern "C" void kernel_launch(void* const* d_in, const int* in_sizes, int n_in,
                              void* d_out, int out_size, void* d_ws, size_t ws_size,
                              hipStream_t stream) {
  const float* x  = (const float*)d_in[0];
  const float* S  = (const float*)d_in[1];
  const float* Wq = (const float*)d_in[2];
  const float* Wk = (const float*)d_in[3];
  const float* Wv = (const float*)d_in[4];
  const float* Wb = (const float*)d_in[5];
  const float* Wo = (const float*)d_in[6];
  const float* g  = (const float*)d_in[7];

  char* w = (char*)d_ws;
  f16*   qkvc    = (f16*)w;                     // 16384*768*2 = 25,165,824
  float* betaArr = (float*)(w + 25165824);      // 16*4*4096*4 =  1,048,576
  float* sums    = (float*)(w + 26214400);      // 2*4096*4    =     32,768
  float* err_sum = sums;
  float* key_sum = sums + 4096;

  float* out  = (float*)d_out;                  // [16,4096,256] fp32
  float* Sout = out + (size_t)16 * 4096 * 256;  // [16,4,64,64]  fp32

  hipMemsetAsync(sums, 0, 32768, stream);
  beta_kernel<<<16384, 256, 0, stream>>>(x, Wb, betaArr);
  for (int c = 0; c < 4; ++c) {
    int m_base = c * 16384;  // row chunk = 4 batches
    gemm_bt<float, f16><<<dim3(6, 128), 256, 0, stream>>>(
        x, 256, m_base, Wq, Wk, Wv, qkvc, 768);
    state_pass<<<dim3(256, 4), 256, 0, stream>>>(qkvc, S, c * 4, betaArr, g,
                                                 err_sum, key_sum);
    gemm_bt<f16, float><<<dim3(2, 128), 256, 0, stream>>>(
        qkvc, 768, 0, Wo, Wo, Wo, out + (size_t)m_base * 256, 256);
  }
  finalize_S<<<64, 256, 0, stream>>>(S, err_sum, key_sum, Sout);
}